// Round 2
// baseline (674.917 us; speedup 1.0000x reference)
//
#include <hip/hip_runtime.h>
#include <math.h>

#define N_PTS 16384
#define K_NBR 16
#define H_DIM 64
#define TS    2048   // kNN LDS tile (points)

// ---------------- xx[i] = sum(x[i]^2), mimicking numpy squares-then-sum ----
__global__ __launch_bounds__(256) void xx_kernel(const float4* __restrict__ x4,
                                                 float* __restrict__ xx) {
    int i = blockIdx.x * 256 + threadIdx.x;
    float4 v = x4[i];
    {
#pragma clang fp contract(off)
        float s0 = v.x * v.x;
        float s1 = v.y * v.y;
        float s2 = v.z * v.z;
        float s3 = v.w * v.w;
        xx[i] = ((s0 + s1) + s2) + s3;
    }
}

// ---------------- brute-force kNN: one row per wave, 4 rows per block ------
__global__ __launch_bounds__(256) void knn_kernel(const float4* __restrict__ x4,
                                                  const float* __restrict__ xx,
                                                  int* __restrict__ knn) {
    __shared__ float4 xs[TS];
    __shared__ float  xxs[TS];
    const int lane = threadIdx.x & 63;
    const int wave = threadIdx.x >> 6;
    const int row  = blockIdx.x * 4 + wave;

    const float4 xi  = x4[row];
    const float  xxi = xx[row];

    // per-lane sorted-descending top-16 (registers, all indices static)
    float val[16];
    int   idx[16];
#pragma unroll
    for (int j = 0; j < 16; ++j) { val[j] = -INFINITY; idx[j] = -1; }
    float tau = -INFINITY;  // wave-shared safe rejection threshold

    for (int t = 0; t < N_PTS / TS; ++t) {
        const int base = t * TS;
        __syncthreads();
        for (int i = threadIdx.x; i < TS; i += 256) {
            xs[i]  = x4[base + i];
            xxs[i] = xx[base + i];
        }
        __syncthreads();

        float thr = fmaxf(tau, val[15]);
        for (int c = lane; c < TS; c += 64) {
            const float4 xj = xs[c];
            // dot as fma chain (BLAS-like), then reference formula order
            float d = fmaf(xi.x, xj.x, fmaf(xi.y, xj.y, fmaf(xi.z, xj.z, xi.w * xj.w)));
            float p = (2.0f * d - xxi) - xxs[c];
            if (p > thr) {
                val[15] = p; idx[15] = base + c;
#pragma unroll
                for (int j = 15; j > 0; --j) {
                    if (val[j] > val[j - 1]) {
                        float tv = val[j]; val[j] = val[j - 1]; val[j - 1] = tv;
                        int   ti = idx[j]; idx[j] = idx[j - 1]; idx[j - 1] = ti;
                    }
                }
                thr = fmaxf(tau, val[15]);
            }
        }
        // refresh tau = max over lanes of per-lane 16th-best (safe lower bound:
        // any lane's 16th-retained <= global 16th)
        float m = val[15];
#pragma unroll
        for (int off = 32; off > 0; off >>= 1) m = fmaxf(m, __shfl_xor(m, off, 64));
        tau = m;
    }

    // merge the 64 sorted lists: 16 rounds of wave-argmax-pop
    int myNbr = 0;
    for (int r = 0; r < K_NBR; ++r) {
        float v  = val[0];
        int   id = idx[0];
#pragma unroll
        for (int off = 32; off > 0; off >>= 1) {
            float ov  = __shfl_xor(v, off, 64);
            int   oid = __shfl_xor(id, off, 64);
            bool take = (ov > v) || (ov == v && (unsigned)oid < (unsigned)id);
            if (take) { v = ov; id = oid; }
        }
        if (lane == r) myNbr = id;
        if (idx[0] == id) {           // column indices are unique -> one popper
#pragma unroll
            for (int j = 0; j < 15; ++j) { val[j] = val[j + 1]; idx[j] = idx[j + 1]; }
            val[15] = -INFINITY; idx[15] = -1;
        }
    }
    if (lane < K_NBR) knn[row * K_NBR + lane] = myNbr;
}

// ---------------- edge-feature MLP: one wave per point, lane = out feature --
__global__ __launch_bounds__(256) void mlp_kernel(const float4* __restrict__ x4,
                                                  const int* __restrict__ knn,
                                                  const float* __restrict__ W1,
                                                  const float* __restrict__ b1,
                                                  const float* __restrict__ W2,
                                                  const float* __restrict__ b2,
                                                  float* __restrict__ out) {
    __shared__ __align__(16) float h1s[4][K_NBR][H_DIM];  // 16 KB
    const int lane = threadIdx.x & 63;
    const int wave = threadIdx.x >> 6;
    const int p    = blockIdx.x * 4 + wave;

    // per-lane weight rows in registers
    float w1r[8];
#pragma unroll
    for (int c = 0; c < 8; ++c) w1r[c] = W1[lane * 8 + c];
    const float b1r = b1[lane];
    const float b2r = b2[lane];
    float w2r[64];
#pragma unroll
    for (int j = 0; j < 64; ++j) w2r[j] = W2[lane * 64 + j];

    const float4 xi = x4[p];

    // layer 1 for all 16 neighbors
    for (int k = 0; k < K_NBR; ++k) {
        const int nb = knn[p * K_NBR + k];
        const float4 xj = x4[nb];
        float h = b1r;
        h = fmaf(w1r[0], xj.x - xi.x, h);
        h = fmaf(w1r[1], xj.y - xi.y, h);
        h = fmaf(w1r[2], xj.z - xi.z, h);
        h = fmaf(w1r[3], xj.w - xi.w, h);
        h = fmaf(w1r[4], xi.x, h);
        h = fmaf(w1r[5], xi.y, h);
        h = fmaf(w1r[6], xi.z, h);
        h = fmaf(w1r[7], xi.w, h);
        h1s[wave][k][lane] = fmaxf(h, 0.0f);
    }
    __syncthreads();

    // layer 2: acc[k] = b2 + sum_h W2[g,h]*h1[k,h], broadcast b128 LDS reads
    float acc[K_NBR];
#pragma unroll
    for (int k = 0; k < K_NBR; ++k) acc[k] = b2r;

#pragma unroll
    for (int h4 = 0; h4 < H_DIM / 4; ++h4) {
#pragma unroll
        for (int k = 0; k < K_NBR; ++k) {
            const float4 hv = *(const float4*)&h1s[wave][k][h4 * 4];
            acc[k] = fmaf(w2r[4 * h4 + 0], hv.x, acc[k]);
            acc[k] = fmaf(w2r[4 * h4 + 1], hv.y, acc[k]);
            acc[k] = fmaf(w2r[4 * h4 + 2], hv.z, acc[k]);
            acc[k] = fmaf(w2r[4 * h4 + 3], hv.w, acc[k]);
        }
    }

    float s = 0.0f;
#pragma unroll
    for (int k = 0; k < K_NBR; ++k) s += fmaxf(acc[k], 0.0f);
    out[p * H_DIM + lane] = s * (1.0f / 16.0f);
}

extern "C" void kernel_launch(void* const* d_in, const int* in_sizes, int n_in,
                              void* d_out, int out_size, void* d_ws, size_t ws_size,
                              hipStream_t stream) {
    (void)in_sizes; (void)n_in; (void)out_size; (void)ws_size;
    const float* x  = (const float*)d_in[0];
    const float* W1 = (const float*)d_in[1];
    const float* b1 = (const float*)d_in[2];
    const float* W2 = (const float*)d_in[3];
    const float* b2 = (const float*)d_in[4];
    float* out = (float*)d_out;

    float* xx  = (float*)d_ws;                                  // N floats
    int*   knn = (int*)((char*)d_ws + N_PTS * sizeof(float));   // N*K ints

    const float4* x4 = (const float4*)x;

    xx_kernel <<<N_PTS / 256, 256, 0, stream>>>(x4, xx);
    knn_kernel<<<N_PTS / 4,   256, 0, stream>>>(x4, xx, knn);
    mlp_kernel<<<N_PTS / 4,   256, 0, stream>>>(x4, knn, W1, b1, W2, b2, out);
}

// Round 3
// 316.900 us; speedup vs baseline: 2.1298x; 2.1298x over previous
//
#include <hip/hip_runtime.h>
#include <math.h>

#define N_PTS 16384
#define K_NBR 16
#define H_DIM 64
#define TS    2048   // kNN LDS tile (points)

// ---------------- xx[i] = sum(x[i]^2), mimicking numpy squares-then-sum ----
__global__ __launch_bounds__(256) void xx_kernel(const float4* __restrict__ x4,
                                                 float* __restrict__ xx) {
    int i = blockIdx.x * 256 + threadIdx.x;
    float4 v = x4[i];
    {
#pragma clang fp contract(off)
        float s0 = v.x * v.x;
        float s1 = v.y * v.y;
        float s2 = v.z * v.z;
        float s3 = v.w * v.w;
        xx[i] = ((s0 + s1) + s2) + s3;
    }
}

// ---------------- brute-force kNN: one row per wave, 4 rows per block ------
// Wave-shared running top-16: lane l (l<16) holds the (l+1)-th largest (val,idx).
// tau (SGPR) = current 16th largest. Hot path: distance + 1 cmp + scalar branch.
__global__ __launch_bounds__(256) void knn_kernel(const float4* __restrict__ x4,
                                                  const float* __restrict__ xx,
                                                  int* __restrict__ knn) {
    __shared__ float4 xs[TS];
    __shared__ float  xxs[TS];
    const int lane = threadIdx.x & 63;
    const int wave = threadIdx.x >> 6;
    const int row  = blockIdx.x * 4 + wave;

    const float4 xi  = x4[row];
    const float  xxi = xx[row];

    float val  = -INFINITY;   // distributed sorted list (lanes 0..15)
    int   vidx = -1;
    float tau  = -INFINITY;   // scalar: val @ lane 15
    const bool lane_lt16 = (lane < 16);

    for (int t = 0; t < N_PTS / TS; ++t) {
        const int base = t * TS;
        __syncthreads();
        for (int i = threadIdx.x; i < TS; i += 256) {
            xs[i]  = x4[base + i];
            xxs[i] = xx[base + i];
        }
        __syncthreads();

        for (int c = lane; c < TS; c += 64) {
            const float4 xj = xs[c];
            // dot as fma chain, then reference formula order (2*d exact)
            float d = fmaf(xi.x, xj.x, fmaf(xi.y, xj.y, fmaf(xi.z, xj.z, xi.w * xj.w)));
            float p = (2.0f * d - xxi) - xxs[c];
            const int cidx = base + c;

            unsigned long long mask = __ballot(p > tau);
            while (mask) {                         // uniform scalar loop, rare
                const int l = __ffsll(mask) - 1;   // lowest lane = lowest index
                const float pb = __uint_as_float(
                    __builtin_amdgcn_readlane(__float_as_uint(p), l));
                const int ib = __builtin_amdgcn_readlane(cidx, l);
                // rank: existing entries with val >= pb stay above (stable ties)
                const int r = __popcll(__ballot(val >= pb));   // r <= 15 since pb > tau
                const float sv = __shfl_up(val, 1, 64);
                const int   si = __shfl_up(vidx, 1, 64);
                if (lane >= r) {
                    val  = (lane == r) ? pb : sv;
                    vidx = (lane == r) ? ib : si;
                }
                if (!lane_lt16) val = -INFINITY;   // keep upper lanes inert
                tau = __uint_as_float(
                    __builtin_amdgcn_readlane(__float_as_uint(val), 15));
                mask &= (mask - 1);                // drop processed lane
                mask &= __ballot(p > tau);         // re-prune with tighter tau
            }
        }
    }

    if (lane_lt16) knn[row * K_NBR + lane] = vidx;
}

// ---------------- edge-feature MLP: one wave per point, lane = out feature --
__global__ __launch_bounds__(256) void mlp_kernel(const float4* __restrict__ x4,
                                                  const int* __restrict__ knn,
                                                  const float* __restrict__ W1,
                                                  const float* __restrict__ b1,
                                                  const float* __restrict__ W2,
                                                  const float* __restrict__ b2,
                                                  float* __restrict__ out) {
    __shared__ __align__(16) float h1s[4][K_NBR][H_DIM];  // 16 KB
    const int lane = threadIdx.x & 63;
    const int wave = threadIdx.x >> 6;
    const int p    = blockIdx.x * 4 + wave;

    // per-lane weight rows in registers
    float w1r[8];
#pragma unroll
    for (int c = 0; c < 8; ++c) w1r[c] = W1[lane * 8 + c];
    const float b1r = b1[lane];
    const float b2r = b2[lane];
    float w2r[64];
#pragma unroll
    for (int j = 0; j < 64; ++j) w2r[j] = W2[lane * 64 + j];

    const float4 xi = x4[p];

    // layer 1 for all 16 neighbors
    for (int k = 0; k < K_NBR; ++k) {
        const int nb = knn[p * K_NBR + k];
        const float4 xj = x4[nb];
        float h = b1r;
        h = fmaf(w1r[0], xj.x - xi.x, h);
        h = fmaf(w1r[1], xj.y - xi.y, h);
        h = fmaf(w1r[2], xj.z - xi.z, h);
        h = fmaf(w1r[3], xj.w - xi.w, h);
        h = fmaf(w1r[4], xi.x, h);
        h = fmaf(w1r[5], xi.y, h);
        h = fmaf(w1r[6], xi.z, h);
        h = fmaf(w1r[7], xi.w, h);
        h1s[wave][k][lane] = fmaxf(h, 0.0f);
    }
    __syncthreads();

    // layer 2: acc[k] = b2 + sum_h W2[g,h]*h1[k,h], broadcast b128 LDS reads
    float acc[K_NBR];
#pragma unroll
    for (int k = 0; k < K_NBR; ++k) acc[k] = b2r;

#pragma unroll
    for (int h4 = 0; h4 < H_DIM / 4; ++h4) {
#pragma unroll
        for (int k = 0; k < K_NBR; ++k) {
            const float4 hv = *(const float4*)&h1s[wave][k][h4 * 4];
            acc[k] = fmaf(w2r[4 * h4 + 0], hv.x, acc[k]);
            acc[k] = fmaf(w2r[4 * h4 + 1], hv.y, acc[k]);
            acc[k] = fmaf(w2r[4 * h4 + 2], hv.z, acc[k]);
            acc[k] = fmaf(w2r[4 * h4 + 3], hv.w, acc[k]);
        }
    }

    float s = 0.0f;
#pragma unroll
    for (int k = 0; k < K_NBR; ++k) s += fmaxf(acc[k], 0.0f);
    out[p * H_DIM + lane] = s * (1.0f / 16.0f);
}

extern "C" void kernel_launch(void* const* d_in, const int* in_sizes, int n_in,
                              void* d_out, int out_size, void* d_ws, size_t ws_size,
                              hipStream_t stream) {
    (void)in_sizes; (void)n_in; (void)out_size; (void)ws_size;
    const float* x  = (const float*)d_in[0];
    const float* W1 = (const float*)d_in[1];
    const float* b1 = (const float*)d_in[2];
    const float* W2 = (const float*)d_in[3];
    const float* b2 = (const float*)d_in[4];
    float* out = (float*)d_out;

    float* xx  = (float*)d_ws;                                  // N floats
    int*   knn = (int*)((char*)d_ws + N_PTS * sizeof(float));   // N*K ints

    const float4* x4 = (const float4*)x;

    xx_kernel <<<N_PTS / 256, 256, 0, stream>>>(x4, xx);
    knn_kernel<<<N_PTS / 4,   256, 0, stream>>>(x4, xx, knn);
    mlp_kernel<<<N_PTS / 4,   256, 0, stream>>>(x4, knn, W1, b1, W2, b2, out);
}